// Round 13
// baseline (57.037 us; speedup 1.0000x reference)
//
#include <hip/hip_runtime.h>
#include <cstddef>

typedef __attribute__((ext_vector_type(8))) short short8v;
typedef __attribute__((ext_vector_type(4))) short short4v;
typedef __attribute__((ext_vector_type(4))) float f32x4;

__device__ __forceinline__ unsigned short f2bf(float f) {
    unsigned u = __float_as_uint(f);
    u = (u + 0x7FFFu + ((u >> 16) & 1u)) >> 16;
    return (unsigned short)u;
}

// ---- prep (verified R4/R6/R7): W[o][d][e][w] fp32 -> Wb frag-stream bf16 ----
// Wb[(g*64+f)*36864 + ks*2048 + nt*512 + lane*8 + j], ks = e*9 + w9
//   = bf16( W[o = g*64+nt*16+(lane&15), d = (lane>>4)*8+j, e = 2f+e, w = w9] )
__global__ __launch_bounds__(256) void prep_w(const float* __restrict__ w,
                                              unsigned short* __restrict__ wb)
{
    const int g  = blockIdx.x >> 6;
    const int f  = blockIdx.x & 63;
    const int e0 = 2 * f;
    const int tid = threadIdx.x;
    __shared__ unsigned short ls[64 * 580];   // pitch 580 breaks power-of-2 banks

    #pragma unroll 4
    for (int i = 0; i < 72; ++i) {
        int fl  = tid + i * 256;           // (o_l,d) x 9 float2
        int od  = fl / 9;
        int f2i = fl - od * 9;
        int o_l = od >> 5;
        int d   = od & 31;
        const float2 v = *reinterpret_cast<const float2*>(
            &w[(size_t)((g * 64 + o_l) * 32 + d) * 1152 + e0 * 9 + f2i * 2]);
        ushort2 hh; hh.x = f2bf(v.x); hh.y = f2bf(v.y);
        *reinterpret_cast<ushort2*>(&ls[o_l * 580 + d * 18 + f2i * 2]) = hh;
    }
    __syncthreads();

    unsigned short* wo = wb + (size_t)(g * 64 + f) * 36864;
    #pragma unroll 2
    for (int i = 0; i < 18; ++i) {
        int oc   = tid + i * 256;          // (ks, nt, lane)
        int ks   = oc >> 8;
        int nt   = (oc >> 6) & 3;
        int lane = oc & 63;
        int li = lane & 15, hi = lane >> 4;
        int e  = (ks >= 9) ? 1 : 0;
        int w9 = ks - 9 * e;
        int o_l = nt * 16 + li;
        short8v vv;
        #pragma unroll
        for (int j = 0; j < 8; ++j)
            vv[j] = (short)ls[o_l * 580 + (hi * 8 + j) * 18 + e * 9 + w9];
        *reinterpret_cast<short8v*>(&wo[(size_t)oc * 8]) = vv;
    }
}

// ---- main: block = (bp,g,f): 2 batches x 64n x 128t, 4 waves (bl,th) 64x64.
// LDS = xs ONLY (21.76 KB). A read directly from wb frag-stream per phase
// (1KB coalesced dwordx4, L2-hot, no prefetch ring). VGPR capped 128 ->
// 4 blocks/CU = 16 waves/CU: TLP hides every latency. 4 barriers/block.
__global__ __launch_bounds__(256, 4) void lconv_mfma(const float* __restrict__ x,
                                                     const unsigned short* __restrict__ wb,
                                                     float* __restrict__ out)
{
    int bid = blockIdx.x;                       // 0..1023
    int lid = (bid & 7) * 128 + (bid >> 3);     // XCD-chunked: 4 siblings share wb slab
    const int bp = lid & 3;
    const int f  = (lid >> 2) & 63;
    const int g  = lid >> 8;
    const int e0 = 2 * f;

    const int tid  = threadIdx.x;
    const int lane = tid & 63;
    const int wv   = tid >> 6;
    const int bl   = wv & 1;        // batch within staged pair
    const int th   = wv >> 1;       // t-half
    const int li   = lane & 15;
    const int hi   = lane >> 4;
    const int t    = tid & 127;     // staging lane -> t
    const int z    = tid >> 7;      // staging batch slot

    __shared__ __align__(16) unsigned short xs[2 * 136 * 40];   // 21760 B only

    // zero pads once: tp in {0..3, 132..135}, both slots, all d
    if (tid < 128) {
        int blz = tid >> 6;
        int r   = (tid >> 3) & 7;
        int dq  = tid & 7;
        int tp  = (r < 4) ? r : (128 + r);
        short4v zz = {0, 0, 0, 0};
        *reinterpret_cast<short4v*>(&xs[(blz * 136 + tp) * 40 + dq * 4]) = zz;
    }

    const unsigned short* wA = wb + (size_t)(g * 64 + f) * 36864;

    f32x4 acc[4][4];
    #pragma unroll
    for (int nt = 0; nt < 4; ++nt)
        #pragma unroll
        for (int tt = 0; tt < 4; ++tt)
            acc[nt][tt] = (f32x4){0.f, 0.f, 0.f, 0.f};

    for (int ec = 0; ec < 2; ++ec) {
        if (ec) __syncthreads();            // prior-phase reads done before overwrite

        // ---- stage x(ec): two 16-float passes (keeps reg peak low) ----
        #pragma unroll
        for (int pass = 0; pass < 2; ++pass) {
            float xr[16];
            #pragma unroll
            for (int dqi = 0; dqi < 4; ++dqi) {
                const int dq = pass * 4 + dqi;
                const float* xp = &x[(size_t)(((bp * 2 + z) * 128 + g * 32 + dq * 4) * 128
                                              + (e0 + ec)) * 128 + t];
                xr[dqi * 4 + 0] = xp[0];
                xr[dqi * 4 + 1] = xp[16384];
                xr[dqi * 4 + 2] = xp[32768];
                xr[dqi * 4 + 3] = xp[49152];
            }
            #pragma unroll
            for (int dqi = 0; dqi < 4; ++dqi) {
                const int dq = pass * 4 + dqi;
                short4v hq;
                hq[0] = (short)f2bf(xr[dqi * 4 + 0]);
                hq[1] = (short)f2bf(xr[dqi * 4 + 1]);
                hq[2] = (short)f2bf(xr[dqi * 4 + 2]);
                hq[3] = (short)f2bf(xr[dqi * 4 + 3]);
                *reinterpret_cast<short4v*>(&xs[(z * 136 + t + 4) * 40 + dq * 4]) = hq;
            }
        }
        __syncthreads();

        #pragma unroll
        for (int w9 = 0; w9 < 9; ++w9) {
            // A-frags: direct global frag-stream read (coalesced 1KB per nt)
            short8v Af[4], Bf[4];
            #pragma unroll
            for (int nt = 0; nt < 4; ++nt)
                Af[nt] = *reinterpret_cast<const short8v*>(
                    &wA[(size_t)((ec * 9 + w9) * 4 + nt) * 512 + lane * 8]);
            #pragma unroll
            for (int tt = 0; tt < 4; ++tt) {
                int tp = th * 64 + tt * 16 + li + w9;
                Bf[tt] = *reinterpret_cast<const short8v*>(
                    &xs[(bl * 136 + tp) * 40 + hi * 8]);
            }
            __builtin_amdgcn_s_setprio(1);
            #pragma unroll
            for (int nt = 0; nt < 4; ++nt)
                #pragma unroll
                for (int tt = 0; tt < 4; ++tt)
                    acc[nt][tt] = __builtin_amdgcn_mfma_f32_16x16x32_bf16(
                        Af[nt], Bf[tt], acc[nt][tt], 0, 0, 0);
            __builtin_amdgcn_s_setprio(0);
        }
    }

    // ---- epilogue: LeakyReLU + store (C: col=lane&15 -> t, row=(lane>>4)*4+j -> n) ----
    const int b = bp * 2 + bl;
    #pragma unroll
    for (int nt = 0; nt < 4; ++nt) {
        #pragma unroll
        for (int tt = 0; tt < 4; ++tt) {
            #pragma unroll
            for (int j = 0; j < 4; ++j) {
                float v = acc[nt][tt][j];
                v = (v >= 0.f) ? v : 0.01f * v;
                int n  = nt * 16 + hi * 4 + j;
                int tc = th * 64 + tt * 16 + li;
                out[(((size_t)(b * 256 + g * 64 + n)) * 64 + f) * 128 + tc] = v;
            }
        }
    }
}

extern "C" void kernel_launch(void* const* d_in, const int* in_sizes, int n_in,
                              void* d_out, int out_size, void* d_ws, size_t ws_size,
                              hipStream_t stream)
{
    const float* x = (const float*)d_in[0];           // (8,128,128,128) fp32
    const float* w = (const float*)d_in[1];           // (256,32,128,9) fp32
    float* out = (float*)d_out;                       // (8,256,64,128) fp32
    unsigned short* wb = (unsigned short*)d_ws;       // 256*36864 bf16 = 18.9 MB

    hipLaunchKernelGGL(prep_w, dim3(256), dim3(256), 0, stream, w, wb);
    hipLaunchKernelGGL(lconv_mfma, dim3(1024), dim3(256), 0, stream, x, wb, out);
}